// Round 5
// baseline (380.445 us; speedup 1.0000x reference)
//
#include <hip/hip_runtime.h>
#include <math.h>

// Problem constants
#define D_   2048
#define H_   512
#define K2D  4096
#define X_   36
#define NCOL 1152   // N * Y = 32*36

// Split-K factors (partials + fused reduce; NO atomics anywhere)
#define Z_MLP 32    // kchunk 128
#define Z_TP  8     // kchunk 256

// ws layout (float offsets), regions reused sequentially (~55 MB; ws >= 576MB)
//  A: HP1 (32x262144) -> TPP (8x1179648=9437184) -> HP2
//  B: TPROJ hi/lo bf16 (589824 + 589824 float-equivalents)
//  C: CAT (2097152)
#define O_A   0u
#define O_B   9437184u
#define O_SB  11534336u
#define O_SO  11534848u
#define O_C   11536384u

typedef __attribute__((ext_vector_type(8))) short bf8_t;   // 8 bf16 (4 VGPRs)
typedef __attribute__((ext_vector_type(4))) float f4_t;    // MFMA accumulator

// fp32 -> bf16 round-to-nearest-even, and back
__device__ __forceinline__ unsigned short f2bf(float f) {
  unsigned u = __float_as_uint(f);
  unsigned r = u + 0x7FFFu + ((u >> 16) & 1u);
  return (unsigned short)(r >> 16);
}
__device__ __forceinline__ float bf2f(unsigned short h) {
  return __uint_as_float(((unsigned)h) << 16);
}

// LDS row stride 40 ushorts = 80 B: 16B-aligned rows; frag-read bank pattern
// is 2-way per phase (free per m136).
#define TSTR 40

// split x into bf16 hi/lo pair, store 8 k-contiguous to LDS
__device__ __forceinline__ void cvt8(unsigned short* Hp, unsigned short* Lp,
                                     float4 a, float4 b) {
  __align__(16) unsigned short h[8], l[8];
  float x[8] = {a.x, a.y, a.z, a.w, b.x, b.y, b.z, b.w};
  #pragma unroll
  for (int j = 0; j < 8; j++) {
    h[j] = f2bf(x[j]);
    l[j] = f2bf(x[j] - bf2f(h[j]));
  }
  *(bf8_t*)Hp = *(bf8_t*)&h[0];
  *(bf8_t*)Lp = *(bf8_t*)&l[0];
}

// register-to-register variant: 8 fp32 -> hi/lo bf8 fragments
__device__ __forceinline__ void cvt8v(bf8_t* H, bf8_t* L, float4 a, float4 b) {
  float x[8] = {a.x, a.y, a.z, a.w, b.x, b.y, b.z, b.w};
  bf8_t hh, ll;
  #pragma unroll
  for (int j = 0; j < 8; j++) {
    unsigned short h = f2bf(x[j]);
    hh[j] = (short)h;
    ll[j] = (short)f2bf(x[j] - bf2f(h));
  }
  *H = hh; *L = ll;
}

// ---------------------------------------------------------------------------
// Split-bf16 MFMA GEMM: Cpart[z] = A@B over z's K-chunk (fp32 in/out).
// 64x64 tile, 256 thr / 4 waves, wave tile 32x32 (2x2 frags of 16x16x32).
// All threads stage both A (2 float4) and B (8-scalar column gather);
// register prefetch double-buffer. amode=1: A rows = concat(fc_t[r/32], fc_d[r]).
// ---------------------------------------------------------------------------
__global__ __launch_bounds__(256, 4) void gemm_mfma64(
    const float* __restrict__ A, const float* __restrict__ A2,
    const float* __restrict__ Bm, float* __restrict__ Cpart,
    int M, int N, int K, int kchunk, int amode)
{
  __shared__ __align__(16) unsigned short AsH[64 * TSTR], AsL[64 * TSTR];
  __shared__ __align__(16) unsigned short BsH[64 * TSTR], BsL[64 * TSTR];
  const int t  = threadIdx.x;
  const int m0 = blockIdx.y << 6;
  const int n0 = blockIdx.x << 6;
  const int k0 = blockIdx.z * kchunk;
  const int kend = k0 + kchunk;
  const int w  = t >> 6;          // wave 0..3
  const int ln = t & 15;
  const int qd = (t >> 4) & 3;
  const int wm = (w >> 1) << 5;   // 0/32
  const int wn = (w & 1) << 5;    // 0/32
  // staging maps
  const int a_row = t >> 2;            // 0..63
  const int a_kq  = (t & 3) << 3;      // 0/8/16/24
  const int b_col = t & 63;
  const int b_kq  = (t >> 6) << 3;     // 0/8/16/24

  f4_t acc[2][2];
  #pragma unroll
  for (int i = 0; i < 2; i++)
    #pragma unroll
    for (int j = 0; j < 2; j++) acc[i][j] = (f4_t)0.f;

  float4 pa0, pa1;
  float  pb[8];

  auto loadA = [&](int kb) {
    int gr = m0 + a_row;
    int gk = kb + a_kq;              // multiple of 8; never straddles 2048
    pa0 = make_float4(0.f, 0.f, 0.f, 0.f);
    pa1 = pa0;
    if (gr < M) {
      const float* src;
      if (amode == 0) src = A + (size_t)gr * K + gk;
      else src = (gk < 2048) ? (A  + ((size_t)(gr >> 5) << 11) + gk)
                             : (A2 + ((size_t)gr << 11) + (gk - 2048));
      pa0 = *(const float4*)src;
      pa1 = *(const float4*)(src + 4);
    }
  };
  auto loadB = [&](int kb) {
    #pragma unroll
    for (int j = 0; j < 8; j++)
      pb[j] = Bm[(size_t)(kb + b_kq + j) * N + n0 + b_col];
  };

  loadA(k0); loadB(k0);

  for (int kb = k0; kb < kend; kb += 32) {
    __syncthreads();
    cvt8(&AsH[a_row * TSTR + a_kq], &AsL[a_row * TSTR + a_kq], pa0, pa1);
    cvt8(&BsH[b_col * TSTR + b_kq], &BsL[b_col * TSTR + b_kq],
         make_float4(pb[0], pb[1], pb[2], pb[3]),
         make_float4(pb[4], pb[5], pb[6], pb[7]));
    __syncthreads();
    if (kb + 32 < kend) { loadA(kb + 32); loadB(kb + 32); }
    bf8_t ah[2], al[2], bh[2], bl[2];
    #pragma unroll
    for (int fm = 0; fm < 2; fm++) {
      int r = (wm + (fm << 4) + ln) * TSTR + (qd << 3);
      ah[fm] = *(const bf8_t*)&AsH[r];
      al[fm] = *(const bf8_t*)&AsL[r];
    }
    #pragma unroll
    for (int fn = 0; fn < 2; fn++) {
      int r = (wn + (fn << 4) + ln) * TSTR + (qd << 3);
      bh[fn] = *(const bf8_t*)&BsH[r];
      bl[fn] = *(const bf8_t*)&BsL[r];
    }
    #pragma unroll
    for (int fm = 0; fm < 2; fm++)
      #pragma unroll
      for (int fn = 0; fn < 2; fn++) {
        acc[fm][fn] = __builtin_amdgcn_mfma_f32_16x16x32_bf16(ah[fm], bh[fn], acc[fm][fn], 0, 0, 0);
        acc[fm][fn] = __builtin_amdgcn_mfma_f32_16x16x32_bf16(ah[fm], bl[fn], acc[fm][fn], 0, 0, 0);
        acc[fm][fn] = __builtin_amdgcn_mfma_f32_16x16x32_bf16(al[fm], bh[fn], acc[fm][fn], 0, 0, 0);
      }
  }
  // C/D layout: row = qd*4+reg, col = ln  [m89-verified]
  float* Cz = Cpart + (size_t)blockIdx.z * M * N;
  #pragma unroll
  for (int fm = 0; fm < 2; fm++) {
    #pragma unroll
    for (int reg = 0; reg < 4; reg++) {
      int gr = m0 + wm + (fm << 4) + (qd << 2) + reg;
      if (gr < M) {
        #pragma unroll
        for (int fn = 0; fn < 2; fn++)
          Cz[(size_t)gr * N + n0 + wn + (fn << 4) + ln] = acc[fm][fn][reg];
      }
    }
  }
}

// ---------------------------------------------------------------------------
// tproj = sum_z TPP[z]  -> emitted as bf16 hi/lo planes (ready MFMA A-frags).
// 576x2048, Z_TP planes in, 2x [576][2048] ushort out.
// ---------------------------------------------------------------------------
__global__ __launch_bounds__(256) void reduce_tp(
    const float* __restrict__ tpp, unsigned short* __restrict__ tH,
    unsigned short* __restrict__ tL)
{
  int idx = blockIdx.x * 256 + threadIdx.x;     // float4 index, 294912 total
  const float4* p = (const float4*)tpp;
  float4 a = p[idx];
  #pragma unroll
  for (int z = 1; z < Z_TP; z++) {
    float4 b = p[idx + (size_t)z * 294912];
    a.x += b.x; a.y += b.y; a.z += b.z; a.w += b.w;
  }
  ushort4 h, l;
  h.x = f2bf(a.x); l.x = f2bf(a.x - bf2f(h.x));
  h.y = f2bf(a.y); l.y = f2bf(a.y - bf2f(h.y));
  h.z = f2bf(a.z); l.z = f2bf(a.z - bf2f(h.z));
  h.w = f2bf(a.w); l.w = f2bf(a.w - bf2f(h.w));
  ((ushort4*)tH)[idx] = h;
  ((ushort4*)tL)[idx] = l;
}

// ---------------------------------------------------------------------------
// scores[row] = relu(sum_z hp[z][row,:] + b1) . W2 + b2
// ---------------------------------------------------------------------------
__global__ __launch_bounds__(256) void mlp_tail_z(
    const float* __restrict__ hp, const float* __restrict__ b1,
    const float* __restrict__ w2, const float* __restrict__ b2,
    float* __restrict__ out)
{
  int row = blockIdx.x;
  int t   = threadIdx.x;
  float v = 0.f;
  #pragma unroll
  for (int q = 0; q < 2; q++) {
    int h = t + (q << 8);
    float s = 0.f;
    #pragma unroll
    for (int z = 0; z < Z_MLP; z++)
      s += hp[(size_t)z * (H_ * 512) + (size_t)row * H_ + h];
    s += b1[h];
    v += fmaxf(s, 0.f) * w2[h];
  }
  #pragma unroll
  for (int off = 32; off > 0; off >>= 1) v += __shfl_down(v, off, 64);
  __shared__ float red[4];
  if ((t & 63) == 0) red[t >> 6] = v;
  __syncthreads();
  if (t == 0) out[row] = red[0] + red[1] + red[2] + red[3] + b2[0];
}

// ---------------------------------------------------------------------------
// Fused per-(b,i): S = tproj[b] @ att_d[b,i]^T (36x36, K=2048), 512 thr /
// 8 waves, per-wave split-K (wave w -> k in [w*256, w*256+256)).
// Fragments loaded DIRECTLY from global (no LDS in K-loop). B (attd, the
// HBM stream) uses a 2-SLOT rotating register pipeline (192B HBM in flight
// per wave -- outstanding-request bound fix, Little's law: 96B/wave gave
// 2.25 TB/s); A (tproj bf16 hi/lo, L2-hot) is 1-deep. kk-loop fully
// unrolled so slot indices are static (no scratch). Then LDS-reduce over
// 8 wave-planes + mask + row/col max + two softmaxes + weighted features.
// ---------------------------------------------------------------------------
__global__ __launch_bounds__(512, 4) void attn_bi(
    const unsigned short* __restrict__ tH,   // [16][36][2048] hi, +1179648 = lo
    const float* __restrict__ attd,
    const int* __restrict__ amt, const int* __restrict__ amd,
    const float* __restrict__ attt, float* __restrict__ cat)
{
  __shared__ float Sp[8][36][37];            // per-wave partial S (42.6 KB)
  __shared__ int   mtv[36], mdv[36];
  __shared__ float mrow[36], mcol[36], twl[36], dwl[36];
  const int bi = blockIdx.x;
  const int b  = bi >> 5;
  const int t  = threadIdx.x;
  const int w  = t >> 6;                     // wave 0..7
  const int ln = t & 15;
  const int qd = (t >> 4) & 3;
  if (t < 36) { mtv[t] = amt[b * 36 + t]; mdv[t] = amd[bi * 36 + t]; }

  const unsigned short* tLo = tH + 1179648;  // lo plane
  const int kw = (w << 8) + (qd << 3);       // wave k-base (256/wave) + k-quad
  const unsigned short* AH[3];
  const unsigned short* AL[3];
  const float* BP[3];
  #pragma unroll
  for (int f = 0; f < 3; f++) {
    int r = f * 16 + ln; if (r > 35) r = 35;   // clamp: rows/cols 36..47 unused
    size_t ao = ((size_t)b * X_ + r) * D_ + kw;
    AH[f] = tH  + ao;
    AL[f] = tLo + ao;
    BP[f] = attd + ((size_t)bi * X_ + r) * D_ + kw;
  }

  f4_t acc[3][3];
  #pragma unroll
  for (int i = 0; i < 3; i++)
    #pragma unroll
    for (int j = 0; j < 3; j++) acc[i][j] = (f4_t)0.f;

  // B: 2-slot rotating prefetch (slots hold iters kk+1, kk+2 during MFMA of kk)
  // A: 1-deep prefetch (L2-hot)
  bf8_t ah[3], al[3];
  float4 pb0[2][3], pb1[2][3];
  #pragma unroll
  for (int f = 0; f < 3; f++) {
    ah[f]      = *(const bf8_t*)AH[f];
    al[f]      = *(const bf8_t*)AL[f];
    pb0[0][f]  = *(const float4*)BP[f];
    pb1[0][f]  = *(const float4*)(BP[f] + 4);
    pb0[1][f]  = *(const float4*)(BP[f] + 32);
    pb1[1][f]  = *(const float4*)(BP[f] + 32 + 4);
  }

  #pragma unroll
  for (int kk = 0; kk < 8; kk++) {           // 8 x K=32 per wave (kchunk 256)
    const int s = kk & 1;                    // static after full unroll
    bf8_t bh[3], bl[3], cah[3], cal[3];
    #pragma unroll
    for (int f = 0; f < 3; f++) {            // consume slot s (iter kk's data)
      cvt8v(&bh[f], &bl[f], pb0[s][f], pb1[s][f]);
      cah[f] = ah[f]; cal[f] = al[f];
    }
    if (kk < 6) {                            // refill slot s with iter kk+2
      const int off2 = (kk + 2) << 5;
      #pragma unroll
      for (int f = 0; f < 3; f++) {
        pb0[s][f] = *(const float4*)(BP[f] + off2);
        pb1[s][f] = *(const float4*)(BP[f] + off2 + 4);
      }
    }
    if (kk < 7) {                            // A prefetch for kk+1 (L2)
      const int off1 = (kk + 1) << 5;
      #pragma unroll
      for (int f = 0; f < 3; f++) {
        ah[f] = *(const bf8_t*)(AH[f] + off1);
        al[f] = *(const bf8_t*)(AL[f] + off1);
      }
    }
    #pragma unroll
    for (int fm = 0; fm < 3; fm++)
      #pragma unroll
      for (int fn = 0; fn < 3; fn++) {
        acc[fm][fn] = __builtin_amdgcn_mfma_f32_16x16x32_bf16(cah[fm], bh[fn], acc[fm][fn], 0, 0, 0);
        acc[fm][fn] = __builtin_amdgcn_mfma_f32_16x16x32_bf16(cah[fm], bl[fn], acc[fm][fn], 0, 0, 0);
        acc[fm][fn] = __builtin_amdgcn_mfma_f32_16x16x32_bf16(cal[fm], bh[fn], acc[fm][fn], 0, 0, 0);
      }
  }

  // scatter per-wave partial S (C/D layout: row=qd*4+reg, col=ln [m89])
  #pragma unroll
  for (int fm = 0; fm < 3; fm++)
    #pragma unroll
    for (int fn = 0; fn < 3; fn++)
      #pragma unroll
      for (int reg = 0; reg < 4; reg++) {
        int x = (fm << 4) + (qd << 2) + reg;
        int y = (fn << 4) + ln;
        if (x < 36 && y < 36) Sp[w][x][y] = acc[fm][fn][reg];
      }
  __syncthreads();
  // cross-wave reduce (w order 0..7 == ascending k) + mask, in place -> Sp[0]
  for (int e = t; e < 1296; e += 512) {
    int x = e / 36, y = e - x * 36;
    float v = Sp[0][x][y];
    #pragma unroll
    for (int z = 1; z < 8; z++) v += Sp[z][x][y];
    Sp[0][x][y] = (mtv[x] != 0 && mdv[y] != 0) ? v : -1e9f;
  }
  __syncthreads();
  if (t < 36) {
    float r = -INFINITY, c = -INFINITY;
    for (int k = 0; k < 36; k++) {
      r = fmaxf(r, Sp[0][t][k]);
      c = fmaxf(c, Sp[0][k][t]);
    }
    mrow[t] = r; mcol[t] = c;
  }
  __syncthreads();
  if (t < 64) {           // wave 0: softmax over row-max -> tw
    float v = (t < 36) ? mrow[t] : -INFINITY;
    float m = v;
    #pragma unroll
    for (int off = 32; off > 0; off >>= 1) m = fmaxf(m, __shfl_xor(m, off, 64));
    float e = (t < 36) ? expf(v - m) : 0.f;
    float s = e;
    #pragma unroll
    for (int off = 32; off > 0; off >>= 1) s += __shfl_xor(s, off, 64);
    if (t < 36) twl[t] = e / s;
  } else if (t < 128) {   // wave 1: softmax over col-max -> dw (concurrent)
    int l = t - 64;
    float v = (l < 36) ? mcol[l] : -INFINITY;
    float m = v;
    #pragma unroll
    for (int off = 32; off > 0; off >>= 1) m = fmaxf(m, __shfl_xor(m, off, 64));
    float e = (l < 36) ? expf(v - m) : 0.f;
    float s = e;
    #pragma unroll
    for (int off = 32; off > 0; off >>= 1) s += __shfl_xor(s, off, 64);
    if (l < 36) dwl[l] = e / s;
  }
  __syncthreads();
  // weighted features -> cat; 512 threads: one target + one distr float4 each
  const float4* at4 = (const float4*)(attt + (size_t)b * X_ * D_);
  const float4* ad4 = (const float4*)(attd + (size_t)bi * X_ * D_);
  float4 t0 = make_float4(0, 0, 0, 0), d0 = t0;
  for (int x = 0; x < 36; x++) {
    float wt = twl[x], wd = dwl[x];
    float4 a = at4[x * 512 + t];
    float4 e = ad4[x * 512 + t];
    t0.x = fmaf(wt, a.x, t0.x);  t0.y = fmaf(wt, a.y, t0.y);
    t0.z = fmaf(wt, a.z, t0.z);  t0.w = fmaf(wt, a.w, t0.w);
    d0.x = fmaf(wd, e.x, d0.x);  d0.y = fmaf(wd, e.y, d0.y);
    d0.z = fmaf(wd, e.z, d0.z);  d0.w = fmaf(wd, e.w, d0.w);
  }
  float4* c4 = (float4*)(cat + (size_t)bi * K2D);
  c4[t] = t0; c4[512 + t] = d0;
}

// ---------------------------------------------------------------------------
// out[b,:] = log_softmax(sb + so) over N=32
// ---------------------------------------------------------------------------
__global__ __launch_bounds__(64) void lsm(
    const float* __restrict__ sb, const float* __restrict__ so,
    float* __restrict__ out)
{
  int b = blockIdx.x, t = threadIdx.x;
  float s = (t < 32) ? sb[b * 32 + t] + so[b * 32 + t] : -INFINITY;
  float m = s;
  #pragma unroll
  for (int off = 32; off > 0; off >>= 1) m = fmaxf(m, __shfl_xor(m, off, 64));
  float e = (t < 32) ? expf(s - m) : 0.f;
  float sum = e;
  #pragma unroll
  for (int off = 32; off > 0; off >>= 1) sum += __shfl_xor(sum, off, 64);
  if (t < 32) out[b * 32 + t] = s - m - logf(sum);
}

extern "C" void kernel_launch(void* const* d_in, const int* in_sizes, int n_in,
                              void* d_out, int out_size, void* d_ws, size_t ws_size,
                              hipStream_t stream)
{
  const float* fc_t  = (const float*)d_in[0];
  const float* fc_d  = (const float*)d_in[1];
  const float* att_t = (const float*)d_in[2];
  const float* att_d = (const float*)d_in[3];
  const int*   am_t  = (const int*)d_in[4];
  const int*   am_d  = (const int*)d_in[5];
  const float* W1    = (const float*)d_in[6];
  const float* b1    = (const float*)d_in[7];
  const float* W2    = (const float*)d_in[8];
  const float* b2    = (const float*)d_in[9];
  const float* Wbil  = (const float*)d_in[10];
  const float* oW1   = (const float*)d_in[11];
  const float* ob1   = (const float*)d_in[12];
  const float* oW2   = (const float*)d_in[13];
  const float* ob2   = (const float*)d_in[14];
  float* ws  = (float*)d_ws;
  float* out = (float*)d_out;

  // 1. base scorer hidden partials: HP1[z] = concat(fc_t, fc_d) @ W1
  gemm_mfma64<<<dim3(8, 8, Z_MLP), 256, 0, stream>>>(fc_t, fc_d, W1, ws + O_A,
                                                     512, 512, 4096, 4096 / Z_MLP, 1);
  // 2. base scores
  mlp_tail_z<<<512, 256, 0, stream>>>(ws + O_A, b1, W2, b2, ws + O_SB);
  // 3. tproj partials: TPP[z] = att_t @ Wbil
  gemm_mfma64<<<dim3(32, 9, Z_TP), 256, 0, stream>>>(att_t, nullptr, Wbil, ws + O_A,
                                                     576, 2048, 2048, 2048 / Z_TP, 0);
  // 4. reduce to bf16 hi/lo tproj planes
  reduce_tp<<<1152, 256, 0, stream>>>(ws + O_A, (unsigned short*)(ws + O_B),
                                      (unsigned short*)(ws + O_B) + 1179648);
  // 5. fused S-gemm + attention + weighted features -> CAT (8 waves/block)
  attn_bi<<<512, 512, 0, stream>>>((const unsigned short*)(ws + O_B), att_d,
                                   am_t, am_d, att_t, ws + O_C);
  // 6. object scorer hidden partials: HP2[z] = CAT @ oW1
  gemm_mfma64<<<dim3(8, 8, Z_MLP), 256, 0, stream>>>(ws + O_C, nullptr, oW1, ws + O_A,
                                                     512, 512, 4096, 4096 / Z_MLP, 0);
  // 7. object scores
  mlp_tail_z<<<512, 256, 0, stream>>>(ws + O_A, ob1, oW2, ob2, ws + O_SO);
  // 8. final log_softmax
  lsm<<<16, 64, 0, stream>>>(ws + O_SB, ws + O_SO, out);
}

// Round 6
// 378.890 us; speedup vs baseline: 1.0041x; 1.0041x over previous
//
#include <hip/hip_runtime.h>
#include <math.h>

// Problem constants
#define D_   2048
#define H_   512
#define K2D  4096
#define X_   36
#define NCOL 1152   // N * Y = 32*36

// Split-K factors (partials + fused reduce; NO atomics anywhere)
#define Z_MLP 32    // kchunk 128
#define Z_TP  8     // kchunk 256

// ws layout (float offsets), regions reused sequentially (~55 MB; ws >= 576MB)
//  A: HP1 (32x262144) -> TPP (8x1179648=9437184) -> HP2
//  B: TPROJ hi/lo bf16 (589824 + 589824 float-equivalents)
//  C: CAT (2097152)
#define O_A   0u
#define O_B   9437184u
#define O_SB  11534336u
#define O_SO  11534848u
#define O_C   11536384u

typedef __attribute__((ext_vector_type(8))) short bf8_t;   // 8 bf16 (4 VGPRs)
typedef __attribute__((ext_vector_type(4))) float f4_t;    // MFMA accumulator

// fp32 -> bf16 round-to-nearest-even, and back
__device__ __forceinline__ unsigned short f2bf(float f) {
  unsigned u = __float_as_uint(f);
  unsigned r = u + 0x7FFFu + ((u >> 16) & 1u);
  return (unsigned short)(r >> 16);
}
__device__ __forceinline__ float bf2f(unsigned short h) {
  return __uint_as_float(((unsigned)h) << 16);
}

// async global->LDS, 16B per lane, dest = wave-uniform base + lane*16
__device__ __forceinline__ void gload16(const void* g, void* l) {
  __builtin_amdgcn_global_load_lds(
      (const __attribute__((address_space(1))) unsigned int*)g,
      (__attribute__((address_space(3))) unsigned int*)l, 16, 0, 0);
}

// LDS row stride 40 ushorts = 80 B: 16B-aligned rows; frag-read bank pattern
// is 2-way per phase (free per m136).
#define TSTR 40

// split x into bf16 hi/lo pair, store 8 k-contiguous to LDS
__device__ __forceinline__ void cvt8(unsigned short* Hp, unsigned short* Lp,
                                     float4 a, float4 b) {
  __align__(16) unsigned short h[8], l[8];
  float x[8] = {a.x, a.y, a.z, a.w, b.x, b.y, b.z, b.w};
  #pragma unroll
  for (int j = 0; j < 8; j++) {
    h[j] = f2bf(x[j]);
    l[j] = f2bf(x[j] - bf2f(h[j]));
  }
  *(bf8_t*)Hp = *(bf8_t*)&h[0];
  *(bf8_t*)Lp = *(bf8_t*)&l[0];
}

// register-to-register variant: 8 fp32 -> hi/lo bf8 fragments
__device__ __forceinline__ void cvt8v(bf8_t* H, bf8_t* L, float4 a, float4 b) {
  float x[8] = {a.x, a.y, a.z, a.w, b.x, b.y, b.z, b.w};
  bf8_t hh, ll;
  #pragma unroll
  for (int j = 0; j < 8; j++) {
    unsigned short h = f2bf(x[j]);
    hh[j] = (short)h;
    ll[j] = (short)f2bf(x[j] - bf2f(h));
  }
  *H = hh; *L = ll;
}

// ---------------------------------------------------------------------------
// Split-bf16 MFMA GEMM: Cpart[z] = A@B over z's K-chunk (fp32 in/out).
// 64x64 tile, 256 thr / 4 waves, wave tile 32x32 (2x2 frags of 16x16x32).
// ---------------------------------------------------------------------------
__global__ __launch_bounds__(256, 4) void gemm_mfma64(
    const float* __restrict__ A, const float* __restrict__ A2,
    const float* __restrict__ Bm, float* __restrict__ Cpart,
    int M, int N, int K, int kchunk, int amode)
{
  __shared__ __align__(16) unsigned short AsH[64 * TSTR], AsL[64 * TSTR];
  __shared__ __align__(16) unsigned short BsH[64 * TSTR], BsL[64 * TSTR];
  const int t  = threadIdx.x;
  const int m0 = blockIdx.y << 6;
  const int n0 = blockIdx.x << 6;
  const int k0 = blockIdx.z * kchunk;
  const int kend = k0 + kchunk;
  const int w  = t >> 6;          // wave 0..3
  const int ln = t & 15;
  const int qd = (t >> 4) & 3;
  const int wm = (w >> 1) << 5;   // 0/32
  const int wn = (w & 1) << 5;    // 0/32
  // staging maps
  const int a_row = t >> 2;            // 0..63
  const int a_kq  = (t & 3) << 3;      // 0/8/16/24
  const int b_col = t & 63;
  const int b_kq  = (t >> 6) << 3;     // 0/8/16/24

  f4_t acc[2][2];
  #pragma unroll
  for (int i = 0; i < 2; i++)
    #pragma unroll
    for (int j = 0; j < 2; j++) acc[i][j] = (f4_t)0.f;

  float4 pa0, pa1;
  float  pb[8];

  auto loadA = [&](int kb) {
    int gr = m0 + a_row;
    int gk = kb + a_kq;              // multiple of 8; never straddles 2048
    pa0 = make_float4(0.f, 0.f, 0.f, 0.f);
    pa1 = pa0;
    if (gr < M) {
      const float* src;
      if (amode == 0) src = A + (size_t)gr * K + gk;
      else src = (gk < 2048) ? (A  + ((size_t)(gr >> 5) << 11) + gk)
                             : (A2 + ((size_t)gr << 11) + (gk - 2048));
      pa0 = *(const float4*)src;
      pa1 = *(const float4*)(src + 4);
    }
  };
  auto loadB = [&](int kb) {
    #pragma unroll
    for (int j = 0; j < 8; j++)
      pb[j] = Bm[(size_t)(kb + b_kq + j) * N + n0 + b_col];
  };

  loadA(k0); loadB(k0);

  for (int kb = k0; kb < kend; kb += 32) {
    __syncthreads();
    cvt8(&AsH[a_row * TSTR + a_kq], &AsL[a_row * TSTR + a_kq], pa0, pa1);
    cvt8(&BsH[b_col * TSTR + b_kq], &BsL[b_col * TSTR + b_kq],
         make_float4(pb[0], pb[1], pb[2], pb[3]),
         make_float4(pb[4], pb[5], pb[6], pb[7]));
    __syncthreads();
    if (kb + 32 < kend) { loadA(kb + 32); loadB(kb + 32); }
    bf8_t ah[2], al[2], bh[2], bl[2];
    #pragma unroll
    for (int fm = 0; fm < 2; fm++) {
      int r = (wm + (fm << 4) + ln) * TSTR + (qd << 3);
      ah[fm] = *(const bf8_t*)&AsH[r];
      al[fm] = *(const bf8_t*)&AsL[r];
    }
    #pragma unroll
    for (int fn = 0; fn < 2; fn++) {
      int r = (wn + (fn << 4) + ln) * TSTR + (qd << 3);
      bh[fn] = *(const bf8_t*)&BsH[r];
      bl[fn] = *(const bf8_t*)&BsL[r];
    }
    #pragma unroll
    for (int fm = 0; fm < 2; fm++)
      #pragma unroll
      for (int fn = 0; fn < 2; fn++) {
        acc[fm][fn] = __builtin_amdgcn_mfma_f32_16x16x32_bf16(ah[fm], bh[fn], acc[fm][fn], 0, 0, 0);
        acc[fm][fn] = __builtin_amdgcn_mfma_f32_16x16x32_bf16(ah[fm], bl[fn], acc[fm][fn], 0, 0, 0);
        acc[fm][fn] = __builtin_amdgcn_mfma_f32_16x16x32_bf16(al[fm], bh[fn], acc[fm][fn], 0, 0, 0);
      }
  }
  // C/D layout: row = qd*4+reg, col = ln  [m89-verified]
  float* Cz = Cpart + (size_t)blockIdx.z * M * N;
  #pragma unroll
  for (int fm = 0; fm < 2; fm++) {
    #pragma unroll
    for (int reg = 0; reg < 4; reg++) {
      int gr = m0 + wm + (fm << 4) + (qd << 2) + reg;
      if (gr < M) {
        #pragma unroll
        for (int fn = 0; fn < 2; fn++)
          Cz[(size_t)gr * N + n0 + wn + (fn << 4) + ln] = acc[fm][fn][reg];
      }
    }
  }
}

// ---------------------------------------------------------------------------
// tproj = sum_z TPP[z]  -> emitted as bf16 hi/lo planes (ready MFMA A-frags).
// ---------------------------------------------------------------------------
__global__ __launch_bounds__(256) void reduce_tp(
    const float* __restrict__ tpp, unsigned short* __restrict__ tH,
    unsigned short* __restrict__ tL)
{
  int idx = blockIdx.x * 256 + threadIdx.x;     // float4 index, 294912 total
  const float4* p = (const float4*)tpp;
  float4 a = p[idx];
  #pragma unroll
  for (int z = 1; z < Z_TP; z++) {
    float4 b = p[idx + (size_t)z * 294912];
    a.x += b.x; a.y += b.y; a.z += b.z; a.w += b.w;
  }
  ushort4 h, l;
  h.x = f2bf(a.x); l.x = f2bf(a.x - bf2f(h.x));
  h.y = f2bf(a.y); l.y = f2bf(a.y - bf2f(h.y));
  h.z = f2bf(a.z); l.z = f2bf(a.z - bf2f(h.z));
  h.w = f2bf(a.w); l.w = f2bf(a.w - bf2f(h.w));
  ((ushort4*)tH)[idx] = h;
  ((ushort4*)tL)[idx] = l;
}

// ---------------------------------------------------------------------------
// scores[row] = relu(sum_z hp[z][row,:] + b1) . W2 + b2
// ---------------------------------------------------------------------------
__global__ __launch_bounds__(256) void mlp_tail_z(
    const float* __restrict__ hp, const float* __restrict__ b1,
    const float* __restrict__ w2, const float* __restrict__ b2,
    float* __restrict__ out)
{
  int row = blockIdx.x;
  int t   = threadIdx.x;
  float v = 0.f;
  #pragma unroll
  for (int q = 0; q < 2; q++) {
    int h = t + (q << 8);
    float s = 0.f;
    #pragma unroll
    for (int z = 0; z < Z_MLP; z++)
      s += hp[(size_t)z * (H_ * 512) + (size_t)row * H_ + h];
    s += b1[h];
    v += fmaxf(s, 0.f) * w2[h];
  }
  #pragma unroll
  for (int off = 32; off > 0; off >>= 1) v += __shfl_down(v, off, 64);
  __shared__ float red[4];
  if ((t & 63) == 0) red[t >> 6] = v;
  __syncthreads();
  if (t == 0) out[row] = red[0] + red[1] + red[2] + red[3] + b2[0];
}

// ---------------------------------------------------------------------------
// Fused per-(b,i): S = tproj[b] @ att_d[b,i]^T (36x36, K=2048), 256 thr /
// 4 waves, per-wave split-K (wave w -> k in [w*512, w*512+512), 16 steps).
// B (attd, the HBM stream) is staged per-wave into double-buffered LDS via
// global_load_lds (DMA path: load issue is a side effect the compiler can't
// sink; vmcnt counts it; inline-asm s_waitcnt vmcnt(0) + sched_barrier once
// per step pins the 2-phase pipeline). Stage k+1 issues BEFORE compute of k,
// so HBM latency hides under MFMA+cvt. Wave-private buffers => NO barriers
// in the K-loop. LDS tile is XOR-swizzled on BOTH sides (source slot
// (lane&7)^(r&7) at stage; same XOR on ds_read addr) to kill the 16-way
// bank conflict of the 128B-stride row-major tile. A (tproj bf16 hi/lo,
// L2-hot) stays as 1-deep register prefetch, covered by the same vmcnt.
// Then LDS-reduce over 4 wave-planes + mask + row/col max + two softmaxes +
// weighted features -> cat[b,i].  Bit-identical math to the R1 87us kernel.
// ---------------------------------------------------------------------------
__global__ __launch_bounds__(256, 2) void attn_bi(
    const unsigned short* __restrict__ tH,   // [16][36][2048] hi, +1179648 = lo
    const float* __restrict__ attd,
    const int* __restrict__ amt, const int* __restrict__ amd,
    const float* __restrict__ attt, float* __restrict__ cat)
{
  __shared__ float Sp[4][36][37];                 // per-wave partial S (21.3 KB)
  __shared__ __align__(16) float Bs[4][2][1280];  // per-wave dbuf B stage (40 KB)
  __shared__ int   mtv[36], mdv[36];
  __shared__ float mrow[36], mcol[36], twl[36], dwl[36];
  const int bi = blockIdx.x;
  const int b  = bi >> 5;
  const int t  = threadIdx.x;
  const int w  = t >> 6;                     // wave 0..3
  const int lane = t & 63;
  const int ln = t & 15;
  const int qd = (t >> 4) & 3;
  if (t < 36) { mtv[t] = amt[b * 36 + t]; mdv[t] = amd[bi * 36 + t]; }

  const unsigned short* tLo = tH + 1179648;  // lo plane
  const int kw = w << 9;                     // wave k-base (512/wave)
  const unsigned short* AH[3];
  const unsigned short* AL[3];
  #pragma unroll
  for (int f = 0; f < 3; f++) {
    int r = f * 16 + ln; if (r > 35) r = 35;   // clamp: rows 36..47 unused
    size_t ao = ((size_t)b * X_ + r) * D_ + kw + (qd << 3);
    AH[f] = tH  + ao;
    AL[f] = tLo + ao;
  }
  const float* Bbase = attd + (size_t)bi * X_ * D_;

  f4_t acc[3][3];
  #pragma unroll
  for (int i = 0; i < 3; i++)
    #pragma unroll
    for (int j = 0; j < 3; j++) acc[i][j] = (f4_t)0.f;

  // stage one K=32 step of B (40 rows x 128B) into Bs[w][cc], swizzled source
  auto stage = [&](int kk, int cc) {
    const int k0 = kw + (kk << 5);
    #pragma unroll
    for (int j = 0; j < 5; j++) {
      int r = j * 8 + (lane >> 3); if (r > 35) r = 35;
      int ss = (lane & 7) ^ (r & 7);         // inverse swizzle on SOURCE
      gload16(Bbase + (size_t)r * D_ + k0 + (ss << 2), &Bs[w][cc][j << 8]);
    }
  };

  bf8_t ah[3], al[3];
  stage(0, 0);
  #pragma unroll
  for (int f = 0; f < 3; f++) {
    ah[f] = *(const bf8_t*)AH[f];
    al[f] = *(const bf8_t*)AL[f];
  }
  asm volatile("s_waitcnt vmcnt(0)" ::: "memory");
  __builtin_amdgcn_sched_barrier(0);

  int c = 0;
  for (int kk = 0; kk < 16; kk++) {          // 16 x K=32 per wave (kchunk 512)
    if (kk < 15) stage(kk + 1, c ^ 1);       // issue next-step DMA first
    bf8_t anH[3], anL[3];
    if (kk < 15) {                           // A register prefetch (L2-hot)
      const int o1 = (kk + 1) << 5;
      #pragma unroll
      for (int f = 0; f < 3; f++) {
        anH[f] = *(const bf8_t*)(AH[f] + o1);
        anL[f] = *(const bf8_t*)(AL[f] + o1);
      }
    }
    // compute from Bs[w][c] (swizzled ds_read_b128, conflict-free)
    #pragma unroll
    for (int fn = 0; fn < 3; fn++) {
      int r = fn * 16 + ln; if (r > 35) r = 35;
      int base = r << 5;
      int s0 = (((qd << 1)    ) ^ (r & 7)) << 2;
      int s1 = (((qd << 1) | 1) ^ (r & 7)) << 2;
      float4 x0 = *(const float4*)&Bs[w][c][base + s0];
      float4 x1 = *(const float4*)&Bs[w][c][base + s1];
      bf8_t bh, bl;
      cvt8v(&bh, &bl, x0, x1);
      #pragma unroll
      for (int fm = 0; fm < 3; fm++) {
        acc[fm][fn] = __builtin_amdgcn_mfma_f32_16x16x32_bf16(ah[fm], bh, acc[fm][fn], 0, 0, 0);
        acc[fm][fn] = __builtin_amdgcn_mfma_f32_16x16x32_bf16(ah[fm], bl, acc[fm][fn], 0, 0, 0);
        acc[fm][fn] = __builtin_amdgcn_mfma_f32_16x16x32_bf16(al[fm], bh, acc[fm][fn], 0, 0, 0);
      }
    }
    asm volatile("s_waitcnt vmcnt(0)" ::: "memory");   // next buffer + A landed
    __builtin_amdgcn_sched_barrier(0);
    c ^= 1;
    if (kk < 15) {
      #pragma unroll
      for (int f = 0; f < 3; f++) { ah[f] = anH[f]; al[f] = anL[f]; }
    }
  }

  // scatter per-wave partial S (C/D layout: row=qd*4+reg, col=ln [m89])
  #pragma unroll
  for (int fm = 0; fm < 3; fm++)
    #pragma unroll
    for (int fn = 0; fn < 3; fn++)
      #pragma unroll
      for (int reg = 0; reg < 4; reg++) {
        int x = (fm << 4) + (qd << 2) + reg;
        int y = (fn << 4) + ln;
        if (x < 36 && y < 36) Sp[w][x][y] = acc[fm][fn][reg];
      }
  __syncthreads();
  // cross-wave reduce (w order 0..3 == ascending k) + mask, in place -> Sp[0]
  for (int e = t; e < 1296; e += 256) {
    int x = e / 36, y = e - x * 36;
    float v = Sp[0][x][y] + Sp[1][x][y] + Sp[2][x][y] + Sp[3][x][y];
    Sp[0][x][y] = (mtv[x] != 0 && mdv[y] != 0) ? v : -1e9f;
  }
  __syncthreads();
  if (t < 36) {
    float r = -INFINITY, c2 = -INFINITY;
    for (int k = 0; k < 36; k++) {
      r  = fmaxf(r,  Sp[0][t][k]);
      c2 = fmaxf(c2, Sp[0][k][t]);
    }
    mrow[t] = r; mcol[t] = c2;
  }
  __syncthreads();
  if (t < 64) {           // wave 0: softmax over row-max -> tw
    float v = (t < 36) ? mrow[t] : -INFINITY;
    float m = v;
    #pragma unroll
    for (int off = 32; off > 0; off >>= 1) m = fmaxf(m, __shfl_xor(m, off, 64));
    float e = (t < 36) ? expf(v - m) : 0.f;
    float s = e;
    #pragma unroll
    for (int off = 32; off > 0; off >>= 1) s += __shfl_xor(s, off, 64);
    if (t < 36) twl[t] = e / s;
  } else if (t < 128) {   // wave 1: softmax over col-max -> dw (concurrent)
    int l = t - 64;
    float v = (l < 36) ? mcol[l] : -INFINITY;
    float m = v;
    #pragma unroll
    for (int off = 32; off > 0; off >>= 1) m = fmaxf(m, __shfl_xor(m, off, 64));
    float e = (l < 36) ? expf(v - m) : 0.f;
    float s = e;
    #pragma unroll
    for (int off = 32; off > 0; off >>= 1) s += __shfl_xor(s, off, 64);
    if (l < 36) dwl[l] = e / s;
  }
  __syncthreads();
  // weighted features -> cat (att_d[b,i] is L2-hot from the gemm phase)
  const float4* at4 = (const float4*)(attt + (size_t)b * X_ * D_);
  const float4* ad4 = (const float4*)(attd + (size_t)bi * X_ * D_);
  float4 t0 = make_float4(0, 0, 0, 0), t1 = t0, d0 = t0, d1 = t0;
  for (int x = 0; x < 36; x++) {
    float wt = twl[x], wd = dwl[x];
    float4 a  = at4[x * 512 + t];
    float4 a2 = at4[x * 512 + t + 256];
    float4 e  = ad4[x * 512 + t];
    float4 e2 = ad4[x * 512 + t + 256];
    t0.x = fmaf(wt, a.x, t0.x);  t0.y = fmaf(wt, a.y, t0.y);
    t0.z = fmaf(wt, a.z, t0.z);  t0.w = fmaf(wt, a.w, t0.w);
    t1.x = fmaf(wt, a2.x, t1.x); t1.y = fmaf(wt, a2.y, t1.y);
    t1.z = fmaf(wt, a2.z, t1.z); t1.w = fmaf(wt, a2.w, t1.w);
    d0.x = fmaf(wd, e.x, d0.x);  d0.y = fmaf(wd, e.y, d0.y);
    d0.z = fmaf(wd, e.z, d0.z);  d0.w = fmaf(wd, e.w, d0.w);
    d1.x = fmaf(wd, e2.x, d1.x); d1.y = fmaf(wd, e2.y, d1.y);
    d1.z = fmaf(wd, e2.z, d1.z); d1.w = fmaf(wd, e2.w, d1.w);
  }
  float4* c4 = (float4*)(cat + (size_t)bi * K2D);
  c4[t] = t0; c4[t + 256] = t1; c4[512 + t] = d0; c4[512 + t + 256] = d1;
}

// ---------------------------------------------------------------------------
// out[b,:] = log_softmax(sb + so) over N=32
// ---------------------------------------------------------------------------
__global__ __launch_bounds__(64) void lsm(
    const float* __restrict__ sb, const float* __restrict__ so,
    float* __restrict__ out)
{
  int b = blockIdx.x, t = threadIdx.x;
  float s = (t < 32) ? sb[b * 32 + t] + so[b * 32 + t] : -INFINITY;
  float m = s;
  #pragma unroll
  for (int off = 32; off > 0; off >>= 1) m = fmaxf(m, __shfl_xor(m, off, 64));
  float e = (t < 32) ? expf(s - m) : 0.f;
  float sum = e;
  #pragma unroll
  for (int off = 32; off > 0; off >>= 1) sum += __shfl_xor(sum, off, 64);
  if (t < 32) out[b * 32 + t] = s - m - logf(sum);
}

extern "C" void kernel_launch(void* const* d_in, const int* in_sizes, int n_in,
                              void* d_out, int out_size, void* d_ws, size_t ws_size,
                              hipStream_t stream)
{
  const float* fc_t  = (const float*)d_in[0];
  const float* fc_d  = (const float*)d_in[1];
  const float* att_t = (const float*)d_in[2];
  const float* att_d = (const float*)d_in[3];
  const int*   am_t  = (const int*)d_in[4];
  const int*   am_d  = (const int*)d_in[5];
  const float* W1    = (const float*)d_in[6];
  const float* b1    = (const float*)d_in[7];
  const float* W2    = (const float*)d_in[8];
  const float* b2    = (const float*)d_in[9];
  const float* Wbil  = (const float*)d_in[10];
  const float* oW1   = (const float*)d_in[11];
  const float* ob1   = (const float*)d_in[12];
  const float* oW2   = (const float*)d_in[13];
  const float* ob2   = (const float*)d_in[14];
  float* ws  = (float*)d_ws;
  float* out = (float*)d_out;

  // 1. base scorer hidden partials: HP1[z] = concat(fc_t, fc_d) @ W1
  gemm_mfma64<<<dim3(8, 8, Z_MLP), 256, 0, stream>>>(fc_t, fc_d, W1, ws + O_A,
                                                     512, 512, 4096, 4096 / Z_MLP, 1);
  // 2. base scores
  mlp_tail_z<<<512, 256, 0, stream>>>(ws + O_A, b1, W2, b2, ws + O_SB);
  // 3. tproj partials: TPP[z] = att_t @ Wbil
  gemm_mfma64<<<dim3(32, 9, Z_TP), 256, 0, stream>>>(att_t, nullptr, Wbil, ws + O_A,
                                                     576, 2048, 2048, 2048 / Z_TP, 0);
  // 4. reduce to bf16 hi/lo tproj planes
  reduce_tp<<<1152, 256, 0, stream>>>(ws + O_A, (unsigned short*)(ws + O_B),
                                      (unsigned short*)(ws + O_B) + 1179648);
  // 5. fused S-gemm + attention + weighted features -> CAT (LDS-staged B)
  attn_bi<<<512, 256, 0, stream>>>((const unsigned short*)(ws + O_B), att_d,
                                   am_t, am_d, att_t, ws + O_C);
  // 6. object scorer hidden partials: HP2[z] = CAT @ oW1
  gemm_mfma64<<<dim3(8, 8, Z_MLP), 256, 0, stream>>>(ws + O_C, nullptr, oW1, ws + O_A,
                                                     512, 512, 4096, 4096 / Z_MLP, 0);
  // 7. object scores
  mlp_tail_z<<<512, 256, 0, stream>>>(ws + O_A, ob1, oW2, ob2, ws + O_SO);
  // 8. final log_softmax
  lsm<<<16, 64, 0, stream>>>(ws + O_SB, ws + O_SO, out);
}

// Round 8
// 373.368 us; speedup vs baseline: 1.0190x; 1.0148x over previous
//
#include <hip/hip_runtime.h>
#include <math.h>

// Problem constants
#define D_   2048
#define H_   512
#define K2D  4096
#define X_   36
#define NCOL 1152   // N * Y = 32*36

// Split-K factors (partials + fused reduce; NO atomics anywhere)
#define Z_MLP 32    // kchunk 128
#define Z_TP  8     // kchunk 256

// ws layout (float offsets), regions reused sequentially (~55 MB; ws >= 576MB)
//  A: HP1 (32x262144) -> TPP (8x1179648=9437184) -> HP2
//  B: TPROJ hi/lo bf16 (589824 + 589824 float-equivalents)
//  C: CAT (2097152)
#define O_A   0u
#define O_B   9437184u
#define O_SB  11534336u
#define O_SO  11534848u
#define O_C   11536384u

typedef __attribute__((ext_vector_type(8))) short bf8_t;   // 8 bf16 (4 VGPRs)
typedef __attribute__((ext_vector_type(4))) float f4_t;    // MFMA accumulator

// fp32 -> bf16 round-to-nearest-even, and back
__device__ __forceinline__ unsigned short f2bf(float f) {
  unsigned u = __float_as_uint(f);
  unsigned r = u + 0x7FFFu + ((u >> 16) & 1u);
  return (unsigned short)(r >> 16);
}
__device__ __forceinline__ float bf2f(unsigned short h) {
  return __uint_as_float(((unsigned)h) << 16);
}

// async global->LDS, 16B per lane, dest = wave-uniform base + lane*16
__device__ __forceinline__ void gload16(const void* g, void* l) {
  __builtin_amdgcn_global_load_lds(
      (const __attribute__((address_space(1))) unsigned int*)g,
      (__attribute__((address_space(3))) unsigned int*)l, 16, 0, 0);
}

// LDS row stride 40 ushorts = 80 B: 16B-aligned rows; frag-read bank pattern
// is 2-way per phase (free per m136).
#define TSTR 40

// split x into bf16 hi/lo pair, store 8 k-contiguous to LDS
__device__ __forceinline__ void cvt8(unsigned short* Hp, unsigned short* Lp,
                                     float4 a, float4 b) {
  __align__(16) unsigned short h[8], l[8];
  float x[8] = {a.x, a.y, a.z, a.w, b.x, b.y, b.z, b.w};
  #pragma unroll
  for (int j = 0; j < 8; j++) {
    h[j] = f2bf(x[j]);
    l[j] = f2bf(x[j] - bf2f(h[j]));
  }
  *(bf8_t*)Hp = *(bf8_t*)&h[0];
  *(bf8_t*)Lp = *(bf8_t*)&l[0];
}

// register-to-register variant: 8 fp32 -> hi/lo bf8 fragments
__device__ __forceinline__ void cvt8v(bf8_t* H, bf8_t* L, float4 a, float4 b) {
  float x[8] = {a.x, a.y, a.z, a.w, b.x, b.y, b.z, b.w};
  bf8_t hh, ll;
  #pragma unroll
  for (int j = 0; j < 8; j++) {
    unsigned short h = f2bf(x[j]);
    hh[j] = (short)h;
    ll[j] = (short)f2bf(x[j] - bf2f(h));
  }
  *H = hh; *L = ll;
}

// ---------------------------------------------------------------------------
// Split-bf16 MFMA GEMM: Cpart[z] = A@B over z's K-chunk (fp32 in/out).
// 64x64 tile, 256 thr / 4 waves, wave tile 32x32 (2x2 frags of 16x16x32).
// ---------------------------------------------------------------------------
__global__ __launch_bounds__(256, 4) void gemm_mfma64(
    const float* __restrict__ A, const float* __restrict__ A2,
    const float* __restrict__ Bm, float* __restrict__ Cpart,
    int M, int N, int K, int kchunk, int amode)
{
  __shared__ __align__(16) unsigned short AsH[64 * TSTR], AsL[64 * TSTR];
  __shared__ __align__(16) unsigned short BsH[64 * TSTR], BsL[64 * TSTR];
  const int t  = threadIdx.x;
  const int m0 = blockIdx.y << 6;
  const int n0 = blockIdx.x << 6;
  const int k0 = blockIdx.z * kchunk;
  const int kend = k0 + kchunk;
  const int w  = t >> 6;          // wave 0..3
  const int ln = t & 15;
  const int qd = (t >> 4) & 3;
  const int wm = (w >> 1) << 5;   // 0/32
  const int wn = (w & 1) << 5;    // 0/32
  // staging maps
  const int a_row = t >> 2;            // 0..63
  const int a_kq  = (t & 3) << 3;      // 0/8/16/24
  const int b_col = t & 63;
  const int b_kq  = (t >> 6) << 3;     // 0/8/16/24

  f4_t acc[2][2];
  #pragma unroll
  for (int i = 0; i < 2; i++)
    #pragma unroll
    for (int j = 0; j < 2; j++) acc[i][j] = (f4_t)0.f;

  float4 pa0, pa1;
  float  pb[8];

  auto loadA = [&](int kb) {
    int gr = m0 + a_row;
    int gk = kb + a_kq;              // multiple of 8; never straddles 2048
    pa0 = make_float4(0.f, 0.f, 0.f, 0.f);
    pa1 = pa0;
    if (gr < M) {
      const float* src;
      if (amode == 0) src = A + (size_t)gr * K + gk;
      else src = (gk < 2048) ? (A  + ((size_t)(gr >> 5) << 11) + gk)
                             : (A2 + ((size_t)gr << 11) + (gk - 2048));
      pa0 = *(const float4*)src;
      pa1 = *(const float4*)(src + 4);
    }
  };
  auto loadB = [&](int kb) {
    #pragma unroll
    for (int j = 0; j < 8; j++)
      pb[j] = Bm[(size_t)(kb + b_kq + j) * N + n0 + b_col];
  };

  loadA(k0); loadB(k0);

  for (int kb = k0; kb < kend; kb += 32) {
    __syncthreads();
    cvt8(&AsH[a_row * TSTR + a_kq], &AsL[a_row * TSTR + a_kq], pa0, pa1);
    cvt8(&BsH[b_col * TSTR + b_kq], &BsL[b_col * TSTR + b_kq],
         make_float4(pb[0], pb[1], pb[2], pb[3]),
         make_float4(pb[4], pb[5], pb[6], pb[7]));
    __syncthreads();
    if (kb + 32 < kend) { loadA(kb + 32); loadB(kb + 32); }
    bf8_t ah[2], al[2], bh[2], bl[2];
    #pragma unroll
    for (int fm = 0; fm < 2; fm++) {
      int r = (wm + (fm << 4) + ln) * TSTR + (qd << 3);
      ah[fm] = *(const bf8_t*)&AsH[r];
      al[fm] = *(const bf8_t*)&AsL[r];
    }
    #pragma unroll
    for (int fn = 0; fn < 2; fn++) {
      int r = (wn + (fn << 4) + ln) * TSTR + (qd << 3);
      bh[fn] = *(const bf8_t*)&BsH[r];
      bl[fn] = *(const bf8_t*)&BsL[r];
    }
    #pragma unroll
    for (int fm = 0; fm < 2; fm++)
      #pragma unroll
      for (int fn = 0; fn < 2; fn++) {
        acc[fm][fn] = __builtin_amdgcn_mfma_f32_16x16x32_bf16(ah[fm], bh[fn], acc[fm][fn], 0, 0, 0);
        acc[fm][fn] = __builtin_amdgcn_mfma_f32_16x16x32_bf16(ah[fm], bl[fn], acc[fm][fn], 0, 0, 0);
        acc[fm][fn] = __builtin_amdgcn_mfma_f32_16x16x32_bf16(al[fm], bh[fn], acc[fm][fn], 0, 0, 0);
      }
  }
  // C/D layout: row = qd*4+reg, col = ln  [m89-verified]
  float* Cz = Cpart + (size_t)blockIdx.z * M * N;
  #pragma unroll
  for (int fm = 0; fm < 2; fm++) {
    #pragma unroll
    for (int reg = 0; reg < 4; reg++) {
      int gr = m0 + wm + (fm << 4) + (qd << 2) + reg;
      if (gr < M) {
        #pragma unroll
        for (int fn = 0; fn < 2; fn++)
          Cz[(size_t)gr * N + n0 + wn + (fn << 4) + ln] = acc[fm][fn][reg];
      }
    }
  }
}

// ---------------------------------------------------------------------------
// tproj = sum_z TPP[z]  -> emitted as bf16 hi/lo planes (ready MFMA A-frags).
// ---------------------------------------------------------------------------
__global__ __launch_bounds__(256) void reduce_tp(
    const float* __restrict__ tpp, unsigned short* __restrict__ tH,
    unsigned short* __restrict__ tL)
{
  int idx = blockIdx.x * 256 + threadIdx.x;     // float4 index, 294912 total
  const float4* p = (const float4*)tpp;
  float4 a = p[idx];
  #pragma unroll
  for (int z = 1; z < Z_TP; z++) {
    float4 b = p[idx + (size_t)z * 294912];
    a.x += b.x; a.y += b.y; a.z += b.z; a.w += b.w;
  }
  ushort4 h, l;
  h.x = f2bf(a.x); l.x = f2bf(a.x - bf2f(h.x));
  h.y = f2bf(a.y); l.y = f2bf(a.y - bf2f(h.y));
  h.z = f2bf(a.z); l.z = f2bf(a.z - bf2f(h.z));
  h.w = f2bf(a.w); l.w = f2bf(a.w - bf2f(h.w));
  ((ushort4*)tH)[idx] = h;
  ((ushort4*)tL)[idx] = l;
}

// ---------------------------------------------------------------------------
// scores[row] = relu(sum_z hp[z][row,:] + b1) . W2 + b2
// ---------------------------------------------------------------------------
__global__ __launch_bounds__(256) void mlp_tail_z(
    const float* __restrict__ hp, const float* __restrict__ b1,
    const float* __restrict__ w2, const float* __restrict__ b2,
    float* __restrict__ out)
{
  int row = blockIdx.x;
  int t   = threadIdx.x;
  float v = 0.f;
  #pragma unroll
  for (int q = 0; q < 2; q++) {
    int h = t + (q << 8);
    float s = 0.f;
    #pragma unroll
    for (int z = 0; z < Z_MLP; z++)
      s += hp[(size_t)z * (H_ * 512) + (size_t)row * H_ + h];
    s += b1[h];
    v += fmaxf(s, 0.f) * w2[h];
  }
  #pragma unroll
  for (int off = 32; off > 0; off >>= 1) v += __shfl_down(v, off, 64);
  __shared__ float red[4];
  if ((t & 63) == 0) red[t >> 6] = v;
  __syncthreads();
  if (t == 0) out[row] = red[0] + red[1] + red[2] + red[3] + b2[0];
}

// ---------------------------------------------------------------------------
// Fused per-(b,i): S = tproj[b] @ att_d[b,i]^T (36x36, K=2048), 256 thr /
// 4 waves.  BLOCK-COOPERATIVE staging: per super-step the whole block DMAs
// [36 rows x K=128] (18 KB, source runs of 512 B -- 4x longer DRAM runs than
// the per-wave variants, which pinned at 2.2 TB/s with 128 B runs) into a
// double-buffered LDS tile via global_load_lds.  Wave w then computes its
// K=32 sub-slice [sc*128 + w*32, +32) -> interleaved split-K; partial S
// summed across waves in order w=0..3.  LDS 16B-slots are XOR-permuted
// (p ^ (r&31)) on BOTH sides (inverse on DMA source, forward on ds_read);
// the permutation stays inside each row's 512B window so DRAM runs remain
// contiguous.  vmcnt(0) + barrier per super-step (each wave drains its own
// DMAs; barrier publishes all 36 rows).  A (tproj bf16 hi/lo, L2-hot) is a
// 1-deep register prefetch.  Epilogue (mask/max/softmax/weighted feats)
// unchanged.
// ---------------------------------------------------------------------------
__global__ __launch_bounds__(256, 2) void attn_bi(
    const unsigned short* __restrict__ tH,   // [16][36][2048] hi, +1179648 = lo
    const float* __restrict__ attd,
    const int* __restrict__ amt, const int* __restrict__ amd,
    const float* __restrict__ attt, float* __restrict__ cat)
{
  __shared__ float Sp[4][36][37];                 // per-wave partial S (21.3 KB)
  __shared__ __align__(16) float Bs[2][36 * 128]; // dbuf staged B (36.9 KB)
  __shared__ int   mtv[36], mdv[36];
  __shared__ float mrow[36], mcol[36], twl[36], dwl[36];
  const int bi = blockIdx.x;
  const int b  = bi >> 5;
  const int t  = threadIdx.x;
  const int w  = t >> 6;                     // wave 0..3
  const int lane = t & 63;
  const int ln = t & 15;
  const int qd = (t >> 4) & 3;
  if (t < 36) { mtv[t] = amt[b * 36 + t]; mdv[t] = amd[bi * 36 + t]; }

  const unsigned short* tLo = tH + 1179648;  // lo plane
  const unsigned short* AH[3];
  const unsigned short* AL[3];
  #pragma unroll
  for (int f = 0; f < 3; f++) {
    int r = f * 16 + ln; if (r > 35) r = 35;   // clamp: rows 36..47 unused
    size_t ao = ((size_t)b * X_ + r) * D_ + (w << 5) + (qd << 3);
    AH[f] = tH  + ao;
    AL[f] = tLo + ao;
  }
  const float* Bbase = attd + (size_t)bi * X_ * D_;

  f4_t acc[3][3];
  #pragma unroll
  for (int i = 0; i < 3; i++)
    #pragma unroll
    for (int j = 0; j < 3; j++) acc[i][j] = (f4_t)0.f;

  // block-cooperative stage of super-chunk sc (K=128): 18 gload16 (2 rows
  // each, 512B source run per row), waves issue 5/5/4/4.
  const int g0 = (w < 2) ? w * 5 : 10 + (w - 2) * 4;
  const int gn = (w < 2) ? 5 : 4;
  auto stage = [&](int sc, int cc) {
    #pragma unroll
    for (int j = 0; j < 5; j++) {
      if (j < gn) {
        int g = g0 + j;
        int r = (g << 1) + (lane >> 5);      // 0..35
        int p = lane & 31;                   // physical 16B slot in row
        int s = p ^ (r & 31);                // logical k-slot (inverse swz)
        gload16(Bbase + (size_t)r * D_ + (sc << 7) + (s << 2),
                &Bs[cc][g << 8]);
      }
    }
  };

  bf8_t ah[3], al[3];
  stage(0, 0);
  #pragma unroll
  for (int f = 0; f < 3; f++) {
    ah[f] = *(const bf8_t*)AH[f];
    al[f] = *(const bf8_t*)AL[f];
  }
  asm volatile("s_waitcnt vmcnt(0)" ::: "memory");
  __syncthreads();

  int c = 0;
  for (int sc = 0; sc < 16; sc++) {          // 16 super-chunks of K=128
    if (sc < 15) stage(sc + 1, c ^ 1);       // issue next-chunk DMA first
    bf8_t anH[3], anL[3];
    if (sc < 15) {                           // A register prefetch (L2-hot)
      const int o1 = (sc + 1) << 7;
      #pragma unroll
      for (int f = 0; f < 3; f++) {
        anH[f] = *(const bf8_t*)(AH[f] + o1);
        anL[f] = *(const bf8_t*)(AL[f] + o1);
      }
    }
    // compute wave w's K=32 slice from Bs[c] (swizzled ds_read_b128)
    #pragma unroll
    for (int fn = 0; fn < 3; fn++) {
      int r = fn * 16 + ln; if (r > 35) r = 35;
      int s0 = (w << 3) | (qd << 1);         // logical slot (even)
      int p0 = s0 ^ (r & 31);
      int p1 = (s0 | 1) ^ (r & 31);
      const float4 x0 = *(const float4*)&Bs[c][((r << 5) + p0) << 2];
      const float4 x1 = *(const float4*)&Bs[c][((r << 5) + p1) << 2];
      bf8_t bh, bl;
      cvt8v(&bh, &bl, x0, x1);
      #pragma unroll
      for (int fm = 0; fm < 3; fm++) {
        acc[fm][fn] = __builtin_amdgcn_mfma_f32_16x16x32_bf16(ah[fm], bh, acc[fm][fn], 0, 0, 0);
        acc[fm][fn] = __builtin_amdgcn_mfma_f32_16x16x32_bf16(ah[fm], bl, acc[fm][fn], 0, 0, 0);
        acc[fm][fn] = __builtin_amdgcn_mfma_f32_16x16x32_bf16(al[fm], bh, acc[fm][fn], 0, 0, 0);
      }
    }
    asm volatile("s_waitcnt vmcnt(0)" ::: "memory");  // own DMAs + A landed
    __syncthreads();                                  // all rows published
    c ^= 1;
    if (sc < 15) {
      #pragma unroll
      for (int f = 0; f < 3; f++) { ah[f] = anH[f]; al[f] = anL[f]; }
    }
  }

  // scatter per-wave partial S (C/D layout: row=qd*4+reg, col=ln [m89])
  #pragma unroll
  for (int fm = 0; fm < 3; fm++)
    #pragma unroll
    for (int fn = 0; fn < 3; fn++)
      #pragma unroll
      for (int reg = 0; reg < 4; reg++) {
        int x = (fm << 4) + (qd << 2) + reg;
        int y = (fn << 4) + ln;
        if (x < 36 && y < 36) Sp[w][x][y] = acc[fm][fn][reg];
      }
  __syncthreads();
  // cross-wave reduce (w order 0..3) + mask, in place -> Sp[0]
  for (int e = t; e < 1296; e += 256) {
    int x = e / 36, y = e - x * 36;
    float v = Sp[0][x][y] + Sp[1][x][y] + Sp[2][x][y] + Sp[3][x][y];
    Sp[0][x][y] = (mtv[x] != 0 && mdv[y] != 0) ? v : -1e9f;
  }
  __syncthreads();
  if (t < 36) {
    float r = -INFINITY, c2 = -INFINITY;
    for (int k = 0; k < 36; k++) {
      r  = fmaxf(r,  Sp[0][t][k]);
      c2 = fmaxf(c2, Sp[0][k][t]);
    }
    mrow[t] = r; mcol[t] = c2;
  }
  __syncthreads();
  if (t < 64) {           // wave 0: softmax over row-max -> tw
    float v = (t < 36) ? mrow[t] : -INFINITY;
    float m = v;
    #pragma unroll
    for (int off = 32; off > 0; off >>= 1) m = fmaxf(m, __shfl_xor(m, off, 64));
    float e = (t < 36) ? expf(v - m) : 0.f;
    float s = e;
    #pragma unroll
    for (int off = 32; off > 0; off >>= 1) s += __shfl_xor(s, off, 64);
    if (t < 36) twl[t] = e / s;
  } else if (t < 128) {   // wave 1: softmax over col-max -> dw (concurrent)
    int l = t - 64;
    float v = (l < 36) ? mcol[l] : -INFINITY;
    float m = v;
    #pragma unroll
    for (int off = 32; off > 0; off >>= 1) m = fmaxf(m, __shfl_xor(m, off, 64));
    float e = (l < 36) ? expf(v - m) : 0.f;
    float s = e;
    #pragma unroll
    for (int off = 32; off > 0; off >>= 1) s += __shfl_xor(s, off, 64);
    if (l < 36) dwl[l] = e / s;
  }
  __syncthreads();
  // weighted features -> cat
  const float4* at4 = (const float4*)(attt + (size_t)b * X_ * D_);
  const float4* ad4 = (const float4*)(attd + (size_t)bi * X_ * D_);
  float4 t0 = make_float4(0, 0, 0, 0), t1 = t0, d0 = t0, d1 = t0;
  for (int x = 0; x < 36; x++) {
    float wt = twl[x], wd = dwl[x];
    float4 a  = at4[x * 512 + t];
    float4 a2 = at4[x * 512 + t + 256];
    float4 e  = ad4[x * 512 + t];
    float4 e2 = ad4[x * 512 + t + 256];
    t0.x = fmaf(wt, a.x, t0.x);  t0.y = fmaf(wt, a.y, t0.y);
    t0.z = fmaf(wt, a.z, t0.z);  t0.w = fmaf(wt, a.w, t0.w);
    t1.x = fmaf(wt, a2.x, t1.x); t1.y = fmaf(wt, a2.y, t1.y);
    t1.z = fmaf(wt, a2.z, t1.z); t1.w = fmaf(wt, a2.w, t1.w);
    d0.x = fmaf(wd, e.x, d0.x);  d0.y = fmaf(wd, e.y, d0.y);
    d0.z = fmaf(wd, e.z, d0.z);  d0.w = fmaf(wd, e.w, d0.w);
    d1.x = fmaf(wd, e2.x, d1.x); d1.y = fmaf(wd, e2.y, d1.y);
    d1.z = fmaf(wd, e2.z, d1.z); d1.w = fmaf(wd, e2.w, d1.w);
  }
  float4* c4 = (float4*)(cat + (size_t)bi * K2D);
  c4[t] = t0; c4[t + 256] = t1; c4[512 + t] = d0; c4[512 + t + 256] = d1;
}

// ---------------------------------------------------------------------------
// out[b,:] = log_softmax(sb + so) over N=32
// ---------------------------------------------------------------------------
__global__ __launch_bounds__(64) void lsm(
    const float* __restrict__ sb, const float* __restrict__ so,
    float* __restrict__ out)
{
  int b = blockIdx.x, t = threadIdx.x;
  float s = (t < 32) ? sb[b * 32 + t] + so[b * 32 + t] : -INFINITY;
  float m = s;
  #pragma unroll
  for (int off = 32; off > 0; off >>= 1) m = fmaxf(m, __shfl_xor(m, off, 64));
  float e = (t < 32) ? expf(s - m) : 0.f;
  float sum = e;
  #pragma unroll
  for (int off = 32; off > 0; off >>= 1) sum += __shfl_xor(sum, off, 64);
  if (t < 32) out[b * 32 + t] = s - m - logf(sum);
}

extern "C" void kernel_launch(void* const* d_in, const int* in_sizes, int n_in,
                              void* d_out, int out_size, void* d_ws, size_t ws_size,
                              hipStream_t stream)
{
  const float* fc_t  = (const float*)d_in[0];
  const float* fc_d  = (const float*)d_in[1];
  const float* att_t = (const float*)d_in[2];
  const float* att_d = (const float*)d_in[3];
  const int*   am_t  = (const int*)d_in[4];
  const int*   am_d  = (const int*)d_in[5];
  const float* W1    = (const float*)d_in[6];
  const float* b1    = (const float*)d_in[7];
  const float* W2    = (const float*)d_in[8];
  const float* b2    = (const float*)d_in[9];
  const float* Wbil  = (const float*)d_in[10];
  const float* oW1   = (const float*)d_in[11];
  const float* ob1   = (const float*)d_in[12];
  const float* oW2   = (const float*)d_in[13];
  const float* ob2   = (const float*)d_in[14];
  float* ws  = (float*)d_ws;
  float* out = (float*)d_out;

  // 1. base scorer hidden partials: HP1[z] = concat(fc_t, fc_d) @ W1
  gemm_mfma64<<<dim3(8, 8, Z_MLP), 256, 0, stream>>>(fc_t, fc_d, W1, ws + O_A,
                                                     512, 512, 4096, 4096 / Z_MLP, 1);
  // 2. base scores
  mlp_tail_z<<<512, 256, 0, stream>>>(ws + O_A, b1, W2, b2, ws + O_SB);
  // 3. tproj partials: TPP[z] = att_t @ Wbil
  gemm_mfma64<<<dim3(32, 9, Z_TP), 256, 0, stream>>>(att_t, nullptr, Wbil, ws + O_A,
                                                     576, 2048, 2048, 2048 / Z_TP, 0);
  // 4. reduce to bf16 hi/lo tproj planes
  reduce_tp<<<1152, 256, 0, stream>>>(ws + O_A, (unsigned short*)(ws + O_B),
                                      (unsigned short*)(ws + O_B) + 1179648);
  // 5. fused S-gemm + attention + weighted features -> CAT (coop staging)
  attn_bi<<<512, 256, 0, stream>>>((const unsigned short*)(ws + O_B), att_d,
                                   am_t, am_d, att_t, ws + O_C);
  // 6. object scorer hidden partials: HP2[z] = CAT @ oW1
  gemm_mfma64<<<dim3(8, 8, Z_MLP), 256, 0, stream>>>(ws + O_C, nullptr, oW1, ws + O_A,
                                                     512, 512, 4096, 4096 / Z_MLP, 0);
  // 7. object scores
  mlp_tail_z<<<512, 256, 0, stream>>>(ws + O_A, ob1, oW2, ob2, ws + O_SO);
  // 8. final log_softmax
  lsm<<<16, 64, 0, stream>>>(ws + O_SB, ws + O_SO, out);
}